// Round 3
// baseline (181.714 us; speedup 1.0000x reference)
//
#include <hip/hip_runtime.h>
#include <math.h>

#define NN      4096
#define NB      256           // blocks; co-residency by capacity (validated r4-r10)
#define TPB     1024          // 16 waves per block
#define WPB     16            // nodes (waves) per block
#define CAP     128           // neighbor slots per node (deg incl self ~42, max ~67)
#define GAMMA   0.99f
#define EPSF    1.1920929e-07f
#define KSTEPS  10
#define SLOTSTR 68            // mailbox slots per node (max deg incl self ~67)
#define MAGIC   0x5AFEC0DE    // coef tag: positive int, != 0..9, != poison (negative)

// ---------------------------------------------------------------------------
// r11: PUSH-mailbox dataflow.
// r10 post-mortem: FETCH returned to ~37 MB (sweep loads ARE LLC-served) but
// steps stayed ~5 us: the sweep issues 256 blocks x 4096 = 1M discrete 8B
// agent-load requests/step; measured ~4.5 ns/request -> the LLC is REQUEST-
// RATE bound. Each block read 4096 entries but needs only ~672.
// Fix: make request count proportional to EDGES. Producers PUSH m_j =
// dinv_j*u_j (8B tagged) into their neighbors' mailboxes (one store/edge,
// 172K stores/step); consumers poll only their OWN ~deg contiguous slots
// (~9 lines/node, wave-coalesced). ~350K requests/step vs r10's 1M.
// Weighted-push trick: consumer caches per-slot coef = s_j + b at setup, so
// one 8B word/edge/step suffices:
//   S1 = sum coef_slot*m_slot, S2 = sum m_slot, k3v = dinv_i*(S1 - s_i*S2).
// Slot assignment: one-time atomicAdd claim per edge (cnt[] zeroed by
// stream-ordered hipMemsetAsync - graph-capture-safe; harness itself uses
// memsetAsync). Producer writes C[i][slot] = (coef, MAGIC) once.
// Correctness carried from r9/r10 (both absmax 0.0):
//   tagged word : value+tag in ONE 8B relaxed agent atomic => no cross-
//                 address ordering anywhere; exact-match tag polling.
//   poison-safe : ws poison 0xAAAAAAAA as int tag is negative != 0..9, != MAGIC.
//   no overrun  : adjacency SYMMETRIC. Slot (g->i) in plane p is overwritten
//                 (tag t+2) by g only after g consumed ALL its t+1 inputs,
//                 incl. i's, which i pushed only after consuming its t inputs,
//                 incl. g's slot@t. So a consumer polling for t never sees t+2.
//   liveness    : publish-then-poll order everywhere; setup stores (claim, C,
//                 M0) are unconditional, no poll precedes them. All 256 blocks
//                 resident by capacity (16 waves, 8.7 KB LDS, ~36 VGPR).
// ws: cnt 16 KB | C 2.23 MB | M0 2.23 MB | M1 2.23 MB  (~6.7 MB total).
// Diagnostic: FETCH_SIZE should stay ~36 MB. If it balloons, agent atomics
// miss LLC -> this family is capped, revert to r8 barrier.
// ---------------------------------------------------------------------------

__device__ __forceinline__ float lo_f(unsigned long long z) {
    return __uint_as_float((unsigned int)z);
}
__device__ __forceinline__ unsigned long long pkVT(float v, int tag) {
    return ((unsigned long long)(unsigned int)tag << 32) |
            (unsigned long long)__float_as_uint(v);
}
__device__ __forceinline__ int tag_of(unsigned long long z) {
    return (int)(unsigned int)(z >> 32);
}

__global__ void __launch_bounds__(TPB) gvin_push(
    const float* __restrict__ adj,  const float* __restrict__ x,
    const float* __restrict__ comms,const float* __restrict__ mask,
    const float* __restrict__ Wr,   const float* __restrict__ br,
    const float* __restrict__ We,   const float* __restrict__ be,
    const float* __restrict__ w_emb,const float* __restrict__ b_emb,
    const float* __restrict__ Wa,   const float* __restrict__ ba,
    int* cnt, unsigned long long* C, unsigned long long* M0,
    unsigned long long* M1, float* __restrict__ out)
{
    __shared__ int nbr[WPB][CAP];               // 8 KB
    __shared__ int lcnt[WPB];
    const int wave = threadIdx.x >> 6;
    const int lane = threadIdx.x & 63;
    const int g = (int)blockIdx.x * WPB + wave;

    if (lane == 0) { lcnt[wave] = 1; nbr[wave][0] = g; }   // self-loop (a_norm = adj+I)

    // ---- Phase 1: adj row scan -> LDS neighbor list (byte-identical to the
    // validated r6 scan; HBM/LLC streaming floor ~10-12 us) ----
    const float4* rowp = (const float4*)(adj + (size_t)g * NN);
#pragma unroll 4
    for (int it = 0; it < 16; ++it) {
        const float4 v = rowp[lane + it * 64];            // coalesced 16B/lane
        const int b4 = (lane + it * 64) * 4;
        if (v.x != 0.0f) { int sl = atomicAdd(&lcnt[wave], 1); if (sl < CAP) nbr[wave][sl] = b4;     }
        if (v.y != 0.0f) { int sl = atomicAdd(&lcnt[wave], 1); if (sl < CAP) nbr[wave][sl] = b4 + 1; }
        if (v.z != 0.0f) { int sl = atomicAdd(&lcnt[wave], 1); if (sl < CAP) nbr[wave][sl] = b4 + 2; }
        if (v.w != 0.0f) { int sl = atomicAdd(&lcnt[wave], 1); if (sl < CAP) nbr[wave][sl] = b4 + 3; }
    }

    // ---- per-node scalars: r = xc@Wr + br ; s = (xc@We + be)@w_emb ----
    float pr = 0.0f, ps = 0.0f;
    if (lane < 32) {
        const float xc = (lane < 16) ? x[g * 16 + lane] : comms[g * 16 + (lane - 16)];
        float we = 0.0f;
#pragma unroll
        for (int c = 0; c < 8; ++c) we += We[lane * 8 + c] * w_emb[c];
        pr = xc * Wr[lane];
        ps = xc * we;
    } else if (lane == 32) {
#pragma unroll
        for (int c = 0; c < 8; ++c) ps += be[c] * w_emb[c];
        pr = br[0];
    }
#pragma unroll
    for (int off = 32; off; off >>= 1) { pr += __shfl_xor(pr, off); ps += __shfl_xor(ps, off); }
    const float r = pr, s = ps;

    const int   deg  = lcnt[wave];
    const int   cl   = deg < CAP ? deg : CAP;
    const float dinv = sqrtf(1.0f / ((float)deg + EPSF));
    const float coef = s + b_emb[0];              // this node's consumer-side coef

    // hoist neighbor indices to registers
    bool val0 = lane < cl;
    bool val1 = 64 + lane < cl;                   // deg max ~67 => <=2 chunks
    const int  j0   = val0 ? nbr[wave][lane] : g;
    const int  j1   = val1 ? nbr[wave][64 + lane] : g;

    float wa[8], bb[8];
#pragma unroll
    for (int c = 0; c < 8; ++c) { wa[c] = Wa[c]; bb[c] = ba[c]; }

    // ---- one-time slot claims (cnt[] zeroed by memsetAsync before launch) --
    int slot0 = 0, slot1 = 0;
    if (val0) slot0 = atomicAdd(cnt + j0, 1);
    if (val1) slot1 = atomicAdd(cnt + j1, 1);
    if (slot0 >= SLOTSTR) val0 = false;           // memory-safety guard (never
    if (slot1 >= SLOTSTR) val1 = false;           // hit: max deg ~67 < 68)
    const size_t e0 = (size_t)j0 * SLOTSTR + slot0;
    const size_t e1 = (size_t)j1 * SLOTSTR + slot1;

    // ---- unconditional setup pushes (no poll precedes: deadlock-free) ----
    // C[i][slot] = (coef_g, MAGIC); M0[i][slot] = (dinv_g * u0, tag 0), u0 = r.
    const float m0 = dinv * r;
    if (val0) {
        __hip_atomic_store(C  + e0, pkVT(coef, MAGIC), __ATOMIC_RELAXED, __HIP_MEMORY_SCOPE_AGENT);
        __hip_atomic_store(M0 + e0, pkVT(m0, 0),       __ATOMIC_RELAXED, __HIP_MEMORY_SCOPE_AGENT);
    }
    if (val1) {
        __hip_atomic_store(C  + e1, pkVT(coef, MAGIC), __ATOMIC_RELAXED, __HIP_MEMORY_SCOPE_AGENT);
        __hip_atomic_store(M1 + e1, pkVT(m0, 0),       __ATOMIC_RELAXED, __HIP_MEMORY_SCOPE_AGENT);
    }
    // NOTE: chunk-1 initial push must also land in M0 (tag 0 lives in plane 0):
    if (val1)
        __hip_atomic_store(M0 + e1, pkVT(m0, 0),       __ATOMIC_RELAXED, __HIP_MEMORY_SCOPE_AGENT);

    // ---- consumer setup: cache per-slot coefs from own mailbox C-slots ----
    const int cs = deg < SLOTSTR ? deg : SLOTSTR; // my mailbox slot count
    const bool cv0 = lane < cs;
    const bool cv1 = 64 + lane < cs;
    const size_t my0 = (size_t)g * SLOTSTR + lane;
    const size_t my1 = (size_t)g * SLOTSTR + 64 + lane;
    float cf0 = 0.0f, cf1 = 0.0f;
    {
        bool n0 = cv0, n1 = cv1;
        while (__any(n0 | n1)) {
            if (n0) {
                const unsigned long long z = __hip_atomic_load(C + my0, __ATOMIC_RELAXED, __HIP_MEMORY_SCOPE_AGENT);
                if (tag_of(z) == MAGIC) { cf0 = lo_f(z); n0 = false; }
            }
            if (n1) {
                const unsigned long long z = __hip_atomic_load(C + my1, __ATOMIC_RELAXED, __HIP_MEMORY_SCOPE_AGENT);
                if (tag_of(z) == MAGIC) { cf1 = lo_f(z); n1 = false; }
            }
            if (__any(n0 | n1)) __builtin_amdgcn_s_sleep(2);
        }
    }

    // ---- Phase 2: 10 VI steps, push + own-mailbox poll, no barrier ----
    float v = 0.0f;
    for (int t = 0; t < KSTEPS; ++t) {
        unsigned long long* Min  = (t & 1) ? M1 : M0;
        unsigned long long* Mout = (t & 1) ? M0 : M1;   // plane for tag t+1
        float m_0 = 0.0f, m_1 = 0.0f;
        bool n0 = cv0, n1 = cv1;
        while (__any(n0 | n1)) {
            if (n0) {
                const unsigned long long z = __hip_atomic_load(Min + my0, __ATOMIC_RELAXED, __HIP_MEMORY_SCOPE_AGENT);
                if (tag_of(z) == t) { m_0 = lo_f(z); n0 = false; }
            }
            if (n1) {
                const unsigned long long z = __hip_atomic_load(Min + my1, __ATOMIC_RELAXED, __HIP_MEMORY_SCOPE_AGENT);
                if (tag_of(z) == t) { m_1 = lo_f(z); n1 = false; }
            }
            if (__any(n0 | n1)) __builtin_amdgcn_s_sleep(2);
        }
        float a1 = cf0 * m_0, a2 = m_0;           // S1 = sum coef*m, S2 = sum m
        if (cv1) { a1 = fmaf(cf1, m_1, a1); a2 += m_1; }
#pragma unroll
        for (int off = 32; off; off >>= 1) { a1 += __shfl_xor(a1, off); a2 += __shfl_xor(a2, off); }
        const float k3v = dinv * (a1 - s * a2);
        v = fmaf(k3v, wa[0], bb[0]);
#pragma unroll
        for (int c = 1; c < 8; ++c) v = fmaxf(v, fmaf(k3v, wa[c], bb[c]));
        // push u_{t+1} BEFORE polling t+1 (deadlock-freedom); u_10 never consumed.
        if (t < KSTEPS - 1) {
            const float m = dinv * (r + GAMMA * v);
            const unsigned long long zw = pkVT(m, t + 1);
            if (val0) __hip_atomic_store(Mout + e0, zw, __ATOMIC_RELAXED, __HIP_MEMORY_SCOPE_AGENT);
            if (val1) __hip_atomic_store(Mout + e1, zw, __ATOMIC_RELAXED, __HIP_MEMORY_SCOPE_AGENT);
        }
    }

    if (lane == 0) out[g] = v + (mask[g] == 0.0f ? -INFINITY : 0.0f);
}

extern "C" void kernel_launch(void* const* d_in, const int* in_sizes, int n_in,
                              void* d_out, int out_size, void* d_ws, size_t ws_size,
                              hipStream_t stream) {
    const float* x     = (const float*)d_in[0];
    const float* comms = (const float*)d_in[1];
    const float* adj   = (const float*)d_in[2];
    const float* mask  = (const float*)d_in[3];
    const float* Wr    = (const float*)d_in[4];
    const float* br    = (const float*)d_in[5];
    const float* We    = (const float*)d_in[6];
    const float* be    = (const float*)d_in[7];
    const float* w_emb = (const float*)d_in[8];
    const float* b_emb = (const float*)d_in[9];
    const float* Wa    = (const float*)d_in[10];
    const float* ba    = (const float*)d_in[11];
    // d_in[12] = k (fixed at 10, hardcoded)

    // ws layout: cnt 16 KB | C | M0 | M1, planes of NN*SLOTSTR u64 (2.23 MB ea)
    char* ws = (char*)d_ws;
    const size_t PLANE = (size_t)NN * SLOTSTR * 8;
    int* cnt               = (int*)ws;
    unsigned long long* C  = (unsigned long long*)(ws + 16384);
    unsigned long long* M0 = (unsigned long long*)(ws + 16384 + PLANE);
    unsigned long long* M1 = (unsigned long long*)(ws + 16384 + 2 * PLANE);
    float* out = (float*)d_out;

    // zero the slot-claim counters (stream-ordered, graph-capture-safe)
    hipMemsetAsync(cnt, 0, (size_t)NN * sizeof(int), stream);

    // PLAIN launch: co-residency by capacity (16 waves, 8.7 KB LDS, ~36 VGPR
    // -> >=2 blocks/CU capacity; all 256 blocks resident). Validated r4-r10.
    gvin_push<<<dim3(NB), dim3(TPB), 0, stream>>>(
        adj, x, comms, mask, Wr, br, We, be, w_emb, b_emb, Wa, ba,
        cnt, C, M0, M1, out);
}

// Round 4
// 164.479 us; speedup vs baseline: 1.1048x; 1.1048x over previous
//
#include <hip/hip_runtime.h>
#include <math.h>

#define NN     4096
#define NB     256            // blocks; co-residency by capacity (validated r4-r11)
#define TPB    1024           // 16 waves per block
#define WPB    16             // nodes (waves) per block
#define CAP    128            // neighbor slots per node (deg incl self ~42, max ~67)
#define GAMMA  0.99f
#define EPSF   1.1920929e-07f // np.finfo(np.float32).eps
#define KSTEPS 10
#define RELSTR 16             // ints per 64B line: one exclusive release line per block

// ---------------------------------------------------------------------------
// r12: coherent VECTOR-PATH sweep + single fence barrier.
// Cross-round diagnosis (r9 5.7us/step scattered-pull, r10 5.0us/step atomic
// sweep, r11 push): 8B AGENT-ATOMIC ops take a per-lane serialized LLC path
// (~4.5ns/lane-request, no wave coalescing) - r10's sweep was perfectly
// contiguous yet 1M lane-atomics/step cost ~4.5us. Additionally r9/r11 (no
// barrier) overlapped the 64MB adjacency stream with the step phase, evicting
// the comm planes (FETCH +45MB / WRITE +63MB of thrash).
// Fixes, keeping r10's validated protocol verbatim:
//  1. Sweep via plain `global_load_dwordx2 ... sc1` inline asm. sc1 is the
//     agent-scope coherence flag (same one the compiler emits for agent
//     atomic loads) but on the NORMAL vector-memory path: 64 lanes x 8B
//     coalesce to 8 line-requests/wave vs 64 lane-atomics. Each load is
//     exactly one 8B tagged word -> no tearing across words.
//     Staleness is PROTOCOL-handled: tag != t => r10's validated 8B-atomic
//     re-poll fallback. The sweep is an optimistic fast path only.
//  2. ONE r8-validated fan-out grid barrier after {phase 1, PD/u0 publish}:
//     separates adjacency streaming from the step-phase LLC working set
//     (the r9/r11 thrash killer), compresses skew so step-0 sweep hits ~all
//     tags, and makes the PD gather a poll-free coherent sweep.
//  3. Sweep layout stride-1024 (thread t handles words t, t+1k, t+2k, t+3k):
//     ds_write_b64 at addr 8*t is 2-way bank aliasing = free (m136); r10's
//     164K conflicts came from 32B-contiguous-per-thread LDS writes.
// Correctness (all pieces individually validated in r4-r11, absmax 0.0):
//   tagged word : (float u, int tag) in ONE 8B word; exact-match tag polling;
//                 no cross-address ordering needed anywhere in the step loop.
//   poison-safe : ws poison 0xAAAAAAAA tag is negative != 0..9; barrier flags
//                 monotonic, poison < 1; PD only read after the barrier.
//   no overrun  : adjacency SYMMETRIC. j overwrites tag t with t+2 only after
//                 j validated all neighbors' t+1 - incl i's, which i publishes
//                 only after validating j's t. A consumer needing tag t can
//                 never see t+2. Parity planes separate odd/even tags.
//   sum order   : gather in consumer's own nbr[] lane order == r8/r10 exactly
//                 (r11's atomic-claim reordering is gone) -> absmax 0.0.
//   visibility  : publish stores vmcnt-drain at __syncthreads before arrival
//                 (r6/r8 chain); post-barrier sc1 sweep reads the LLC point
//                 the atomic stores committed to.
// ---------------------------------------------------------------------------

union F2U { unsigned long long u; float2 f; };

__device__ __forceinline__ unsigned long long pk2(float lo, float hi) {
    return ((unsigned long long)__float_as_uint(hi) << 32) |
            (unsigned long long)__float_as_uint(lo);
}
__device__ __forceinline__ float lo_f(unsigned long long z) {
    return __uint_as_float((unsigned int)z);
}
__device__ __forceinline__ float hi_f(unsigned long long z) {
    return __uint_as_float((unsigned int)(z >> 32));
}
__device__ __forceinline__ unsigned long long pkVT(float v, int tag) {
    return ((unsigned long long)(unsigned int)tag << 32) |
            (unsigned long long)__float_as_uint(v);
}
__device__ __forceinline__ int tag_of(unsigned long long z) {
    return (int)(unsigned int)(z >> 32);
}

// r8's fan-out-release grid barrier, verbatim (validated absmax 0.0 r4-r8).
__device__ __forceinline__ void grid_barrier(int* arr, int* rel, int k) {
    __syncthreads();                      // drains every wave's global stores
    if (threadIdx.x == 0)
        __hip_atomic_store(arr + blockIdx.x, k, __ATOMIC_RELAXED,
                           __HIP_MEMORY_SCOPE_AGENT);
    if (blockIdx.x == 0) {
        if (threadIdx.x < 64) {           // master wave: detect all arrivals
            const int base = threadIdx.x * 4;
            for (;;) {
                const int a0 = __hip_atomic_load(arr + base + 0, __ATOMIC_RELAXED, __HIP_MEMORY_SCOPE_AGENT);
                const int a1 = __hip_atomic_load(arr + base + 1, __ATOMIC_RELAXED, __HIP_MEMORY_SCOPE_AGENT);
                const int a2 = __hip_atomic_load(arr + base + 2, __ATOMIC_RELAXED, __HIP_MEMORY_SCOPE_AGENT);
                const int a3 = __hip_atomic_load(arr + base + 3, __ATOMIC_RELAXED, __HIP_MEMORY_SCOPE_AGENT);
                if (__all((a0 >= k) && (a1 >= k) && (a2 >= k) && (a3 >= k))) break;
                __builtin_amdgcn_s_sleep(1);
            }
#pragma unroll
            for (int i = 0; i < 4; ++i)   // fan-out release: 4 exclusive lines/lane
                __hip_atomic_store(rel + (size_t)(base + i) * RELSTR, k,
                                   __ATOMIC_RELAXED, __HIP_MEMORY_SCOPE_AGENT);
        }
    } else if (threadIdx.x == 0) {        // spinner: poll own exclusive line only
        while (__hip_atomic_load(rel + (size_t)blockIdx.x * RELSTR,
                                 __ATOMIC_RELAXED, __HIP_MEMORY_SCOPE_AGENT) < k)
            __builtin_amdgcn_s_sleep(1);
    }
    __syncthreads();                      // release whole block
}

__global__ void __launch_bounds__(TPB) gvin_vsweep(
    const float* __restrict__ adj,  const float* __restrict__ x,
    const float* __restrict__ comms,const float* __restrict__ mask,
    const float* __restrict__ Wr,   const float* __restrict__ br,
    const float* __restrict__ We,   const float* __restrict__ be,
    const float* __restrict__ w_emb,const float* __restrict__ b_emb,
    const float* __restrict__ Wa,   const float* __restrict__ ba,
    int* arr, int* rel,
    unsigned long long* PD, unsigned long long* U0, unsigned long long* U1,
    float* __restrict__ out)
{
    __shared__ int nbr[WPB][CAP];               // 8 KB
    __shared__ int lcnt[WPB];
    __shared__ unsigned long long ULDS[NN];     // 32 KB: plane copy (PD, then U)
    const int wave = threadIdx.x >> 6;
    const int lane = threadIdx.x & 63;
    const int tid  = (int)threadIdx.x;
    const int g = (int)blockIdx.x * WPB + wave;

    if (lane == 0) { lcnt[wave] = 1; nbr[wave][0] = g; }   // self-loop (a_norm = adj+I)

    // ---- Phase 1: adj row scan -> LDS neighbor list (byte-identical to the
    // validated r6 scan; HBM/LLC streaming floor ~10-12 us) ----
    const float4* rowp = (const float4*)(adj + (size_t)g * NN);
#pragma unroll 4
    for (int it = 0; it < 16; ++it) {
        const float4 v = rowp[lane + it * 64];            // coalesced 16B/lane
        const int b4 = (lane + it * 64) * 4;
        if (v.x != 0.0f) { int sl = atomicAdd(&lcnt[wave], 1); if (sl < CAP) nbr[wave][sl] = b4;     }
        if (v.y != 0.0f) { int sl = atomicAdd(&lcnt[wave], 1); if (sl < CAP) nbr[wave][sl] = b4 + 1; }
        if (v.z != 0.0f) { int sl = atomicAdd(&lcnt[wave], 1); if (sl < CAP) nbr[wave][sl] = b4 + 2; }
        if (v.w != 0.0f) { int sl = atomicAdd(&lcnt[wave], 1); if (sl < CAP) nbr[wave][sl] = b4 + 3; }
    }

    // ---- per-node scalars: r = xc@Wr + br ; s = (xc@We + be)@w_emb ----
    float pr = 0.0f, ps = 0.0f;
    if (lane < 32) {
        const float xc = (lane < 16) ? x[g * 16 + lane] : comms[g * 16 + (lane - 16)];
        float we = 0.0f;
#pragma unroll
        for (int c = 0; c < 8; ++c) we += We[lane * 8 + c] * w_emb[c];
        pr = xc * Wr[lane];
        ps = xc * we;
    } else if (lane == 32) {
#pragma unroll
        for (int c = 0; c < 8; ++c) ps += be[c] * w_emb[c];
        pr = br[0];
    }
#pragma unroll
    for (int off = 32; off; off >>= 1) { pr += __shfl_xor(pr, off); ps += __shfl_xor(ps, off); }
    const float r = pr, s = ps;

    const int   deg  = lcnt[wave];
    const int   cl   = deg < CAP ? deg : CAP;
    const float dinv = sqrtf(1.0f / ((float)deg + EPSF));
    const float p    = dinv * (s + b_emb[0]);

    // hoist neighbor indices to registers: steps touch nbr[] no more
    const bool val0 = lane < cl;
    const bool val1 = 64 + lane < cl;                 // deg max ~67 => <=2 chunks
    const int  j0   = val0 ? nbr[wave][lane] : g;
    const int  j1   = val1 ? nbr[wave][64 + lane] : g;

    float wa[8], bb[8];
#pragma unroll
    for (int c = 0; c < 8; ++c) { wa[c] = Wa[c]; bb[c] = ba[c]; }

    // ---- publish PD and u0 = r (tag 0), then ONE fence barrier ----
    if (lane == 0) {
        __hip_atomic_store(PD + g, pk2(p, dinv), __ATOMIC_RELAXED, __HIP_MEMORY_SCOPE_AGENT);
        __hip_atomic_store(U0 + g, pkVT(r, 0),   __ATOMIC_RELAXED, __HIP_MEMORY_SCOPE_AGENT);
    }
    grid_barrier(arr, rel, 1);    // all PD/U0 visible; streaming phase done

    // ---- PD sweep (poll-free: barrier guarantees); coherent vector path ----
    {
        unsigned long long w0, w1, w2, w3;
        asm volatile(
            "global_load_dwordx2 %0, %4, off sc1\n\t"
            "global_load_dwordx2 %1, %5, off sc1\n\t"
            "global_load_dwordx2 %2, %6, off sc1\n\t"
            "global_load_dwordx2 %3, %7, off sc1\n\t"
            "s_waitcnt vmcnt(0)"
            : "=&v"(w0), "=&v"(w1), "=&v"(w2), "=&v"(w3)
            : "v"(PD + tid), "v"(PD + tid + 1024),
              "v"(PD + tid + 2048), "v"(PD + tid + 3072)
            : "memory");
        ULDS[tid] = w0; ULDS[tid + 1024] = w1;
        ULDS[tid + 2048] = w2; ULDS[tid + 3072] = w3;
    }
    __syncthreads();
    float p0 = 0.0f, d0 = 0.0f, p1 = 0.0f, d1 = 0.0f;
    if (val0) { const unsigned long long z = ULDS[j0]; p0 = lo_f(z); d0 = hi_f(z); }
    if (val1) { const unsigned long long z = ULDS[j1]; p1 = lo_f(z); d1 = hi_f(z); }

    // ---- Phase 2: 10 VI steps; optimistic coherent sweep + tag check,
    // atomic re-poll fallback for stragglers only. No per-step barrier. ----
    float v = 0.0f;
    for (int t = 0; t < KSTEPS; ++t) {
        unsigned long long* Uin  = (t & 1) ? U1 : U0;
        unsigned long long* Uout = (t & 1) ? U0 : U1;

        __syncthreads();                          // ULDS free (prev readers done)
        {
            unsigned long long w0, w1, w2, w3;
            asm volatile(
                "global_load_dwordx2 %0, %4, off sc1\n\t"
                "global_load_dwordx2 %1, %5, off sc1\n\t"
                "global_load_dwordx2 %2, %6, off sc1\n\t"
                "global_load_dwordx2 %3, %7, off sc1\n\t"
                "s_waitcnt vmcnt(0)"
                : "=&v"(w0), "=&v"(w1), "=&v"(w2), "=&v"(w3)
                : "v"(Uin + tid), "v"(Uin + tid + 1024),
                  "v"(Uin + tid + 2048), "v"(Uin + tid + 3072)
                : "memory");
            ULDS[tid] = w0; ULDS[tid + 1024] = w1;
            ULDS[tid + 2048] = w2; ULDS[tid + 3072] = w3;
        }
        __syncthreads();                          // copy complete

        unsigned long long z0 = ULDS[j0];
        unsigned long long z1 = ULDS[j1];
        bool n0 = val0 && (tag_of(z0) != t);      // validate ONLY needed entries
        bool n1 = val1 && (tag_of(z1) != t);
        while (__any(n0 | n1)) {                  // straggler subset: atomic re-poll
            if (n0) {
                z0 = __hip_atomic_load(Uin + j0, __ATOMIC_RELAXED, __HIP_MEMORY_SCOPE_AGENT);
                n0 = (tag_of(z0) != t);
            }
            if (n1) {
                z1 = __hip_atomic_load(Uin + j1, __ATOMIC_RELAXED, __HIP_MEMORY_SCOPE_AGENT);
                n1 = (tag_of(z1) != t);
            }
            if (__any(n0 | n1)) __builtin_amdgcn_s_sleep(1);
        }

        const float u0f = val0 ? lo_f(z0) : 0.0f; // sum order == r8/r10 (absmax 0.0)
        float a1 = p0 * u0f, a2 = d0 * u0f;       // S1 = sum p_j u_j, S2 = sum dinv_j u_j
        if (val1) { const float u1f = lo_f(z1); a1 = fmaf(p1, u1f, a1); a2 = fmaf(d1, u1f, a2); }
#pragma unroll
        for (int off = 32; off; off >>= 1) { a1 += __shfl_xor(a1, off); a2 += __shfl_xor(a2, off); }
        const float k3v = dinv * (a1 - s * a2);
        v = fmaf(k3v, wa[0], bb[0]);
#pragma unroll
        for (int c = 1; c < 8; ++c) v = fmaxf(v, fmaf(k3v, wa[c], bb[c]));
        // publish u_{t+1} BEFORE the next sweep (publish-then-poll order is the
        // deadlock-freedom requirement); u_10 is never consumed -> skip.
        if (t < KSTEPS - 1 && lane == 0) {
            __hip_atomic_store(Uout + g, pkVT(r + GAMMA * v, t + 1),
                               __ATOMIC_RELAXED, __HIP_MEMORY_SCOPE_AGENT);
        }
    }

    if (lane == 0) out[g] = v + (mask[g] == 0.0f ? -INFINITY : 0.0f);
}

extern "C" void kernel_launch(void* const* d_in, const int* in_sizes, int n_in,
                              void* d_out, int out_size, void* d_ws, size_t ws_size,
                              hipStream_t stream) {
    const float* x     = (const float*)d_in[0];
    const float* comms = (const float*)d_in[1];
    const float* adj   = (const float*)d_in[2];
    const float* mask  = (const float*)d_in[3];
    const float* Wr    = (const float*)d_in[4];
    const float* br    = (const float*)d_in[5];
    const float* We    = (const float*)d_in[6];
    const float* be    = (const float*)d_in[7];
    const float* w_emb = (const float*)d_in[8];
    const float* b_emb = (const float*)d_in[9];
    const float* Wa    = (const float*)d_in[10];
    const float* ba    = (const float*)d_in[11];
    // d_in[12] = k (fixed at 10, hardcoded)

    // ws: arr 4KB | rel 16KB | PD 32KB | U0 32KB | U1 32KB  (~116 KB total).
    // Poison-safe, no memset needed (barrier flags monotonic; tags negative;
    // PD read only after barrier).
    char* ws = (char*)d_ws;
    int* arr               = (int*)(ws + 0);
    int* rel               = (int*)(ws + 4096);
    unsigned long long* PD = (unsigned long long*)(ws + 4096 + 16384);
    unsigned long long* U0 = (unsigned long long*)(ws + 4096 + 16384 + (size_t)NN * 8);
    unsigned long long* U1 = (unsigned long long*)(ws + 4096 + 16384 + 2 * (size_t)NN * 8);
    float* out = (float*)d_out;

    // PLAIN launch: co-residency by capacity (16 waves, ~41 KB LDS of 160 KB,
    // ~40 VGPR -> 1+ block/CU; all 256 blocks resident). Validated r4-r11.
    gvin_vsweep<<<dim3(NB), dim3(TPB), 0, stream>>>(
        adj, x, comms, mask, Wr, br, We, be, w_emb, b_emb, Wa, ba,
        arr, rel, PD, U0, U1, out);
}

// Round 5
// 153.404 us; speedup vs baseline: 1.1845x; 1.0722x over previous
//
#include <hip/hip_runtime.h>
#include <math.h>

#define NN     4096
#define NB     256            // phase-1 blocks (full machine for 64MB stream)
#define TPB    1024           // 16 waves per block
#define WPB    16             // nodes per phase-1 block
#define CAP    128            // phase-1 LDS neighbor slots
#define SLOT   80             // published CSR slots/node (max deg ~67, 6-sigma margin)
#define NB2    32             // phase-2 (surviving) blocks
#define NPB2   128            // nodes per phase-2 block (NB2*NPB2 == NN)
#define MAXE   10             // CSR slots per sub-thread (8 subs x 10 = 80 = SLOT)
#define GAMMA  0.99f
#define EPSF   1.1920929e-07f
#define KSTEPS 10
#define RELSTR 16             // ints per 64B line: exclusive release line per block

// ---------------------------------------------------------------------------
// r13: BLOCK-RETIREMENT two-phase design.
// r12 post-mortem: data clean (FETCH 36MB, absmax 0.0 - sc1 vector loads
// provably observe agent-atomic stores after a barrier) but steps still ~5us:
// 256 blocks x 32KB plane sweep = 8MB + 131K line-requests per step, plus a
// scattered straggler-poll tail. Communication cost scales with PARTICIPANT
// COUNT; phase 2's compute is only 688K FLOP/step.
// Design: phase 1 on all 256 blocks (adjacency scan needs full machine) ->
// publish {PD=(p,dinv), RS=(r,s), u0, CSR row, deg} -> r8-validated arrival
// barrier -> 224 blocks EXIT. 32 survivors own 128 nodes each (8 thr/node,
// <=10 reg-held edges/thread) and run 10 steps with:
//   - 32-block barrier (r8 fan-out design at 1/8 scale: detect 32 flags on
//     2 lines, release 32 exclusive lines) ~1us vs 4us,
//   - 16KB u-plane sweep via the r12-VALIDATED sc1 vector path; barrier
//     guarantees freshness => NO tags, NO fallback polling,
//   - compute: 10 LDS gathers + 20 FMA/thread + 3-round 8-lane shuffle.
// Validated pieces reused verbatim: barrier visibility chain (r4-r8: data
// stores vmcnt-drained at __syncthreads -> arrival -> detect -> release ->
// spinner -> consumer), sc1-sweep-after-barrier (r12 PD sweep, absmax 0.0),
// poison safety (flags monotonic + poison negative; planes read only after
// the barrier that orders their writes; CSR clamp slot0 always written).
// Retirement: arrival store AFTER __syncthreads, then return (posted stores
// complete independently of wave termination).
// ---------------------------------------------------------------------------

__device__ __forceinline__ unsigned long long pk2(float lo, float hi) {
    return ((unsigned long long)__float_as_uint(hi) << 32) |
            (unsigned long long)__float_as_uint(lo);
}
__device__ __forceinline__ float lo_f(unsigned long long z) {
    return __uint_as_float((unsigned int)z);
}
__device__ __forceinline__ float hi_f(unsigned long long z) {
    return __uint_as_float((unsigned int)(z >> 32));
}

// 32-participant barrier: r8's fan-out-release design at 1/8 scale.
__device__ __forceinline__ void grid_barrier32(int* arr, int* rel, int k) {
    __syncthreads();                      // drains every wave's global stores
    if (threadIdx.x == 0)
        __hip_atomic_store(arr + blockIdx.x, k, __ATOMIC_RELAXED,
                           __HIP_MEMORY_SCOPE_AGENT);
    if (blockIdx.x == 0) {
        if (threadIdx.x < 64) {           // master wave: detect 32 arrivals
            for (;;) {
                int a = k;
                if (threadIdx.x < NB2)
                    a = __hip_atomic_load(arr + threadIdx.x, __ATOMIC_RELAXED,
                                          __HIP_MEMORY_SCOPE_AGENT);
                if (__all(a >= k)) break;
                __builtin_amdgcn_s_sleep(1);
            }
            if (threadIdx.x < NB2)        // fan-out release: exclusive lines
                __hip_atomic_store(rel + (size_t)threadIdx.x * RELSTR, k,
                                   __ATOMIC_RELAXED, __HIP_MEMORY_SCOPE_AGENT);
        }
    } else if (threadIdx.x == 0) {        // spinner: poll own exclusive line
        while (__hip_atomic_load(rel + (size_t)blockIdx.x * RELSTR,
                                 __ATOMIC_RELAXED, __HIP_MEMORY_SCOPE_AGENT) < k)
            __builtin_amdgcn_s_sleep(1);
    }
    __syncthreads();                      // release whole block
}

__global__ void __launch_bounds__(TPB) gvin_retire(
    const float* __restrict__ adj,  const float* __restrict__ x,
    const float* __restrict__ comms,const float* __restrict__ mask,
    const float* __restrict__ Wr,   const float* __restrict__ br,
    const float* __restrict__ We,   const float* __restrict__ be,
    const float* __restrict__ w_emb,const float* __restrict__ b_emb,
    const float* __restrict__ Wa,   const float* __restrict__ ba,
    int* arr, int* rel,
    unsigned long long* PD, unsigned long long* RS,
    float* UF0, float* UF1, int* CNT, int* CSRG,
    float* __restrict__ out)
{
    __shared__ int nbr[WPB][CAP];               // 8 KB
    __shared__ int lcnt[WPB];
    __shared__ unsigned long long PDL[NN];      // 32 KB (p,dinv) plane copy
    __shared__ float UL[NN];                    // 16 KB u-plane copy
    const int tid  = (int)threadIdx.x;
    const int wave = tid >> 6;
    const int lane = tid & 63;
    const int g = (int)blockIdx.x * WPB + wave;

    if (lane == 0) { lcnt[wave] = 1; nbr[wave][0] = g; }   // self-loop (a_norm = adj+I)

    // ---- Phase 1: adj row scan -> LDS neighbor list (verbatim r6 scan) ----
    const float4* rowp = (const float4*)(adj + (size_t)g * NN);
#pragma unroll 4
    for (int it = 0; it < 16; ++it) {
        const float4 v = rowp[lane + it * 64];            // coalesced 16B/lane
        const int b4 = (lane + it * 64) * 4;
        if (v.x != 0.0f) { int sl = atomicAdd(&lcnt[wave], 1); if (sl < CAP) nbr[wave][sl] = b4;     }
        if (v.y != 0.0f) { int sl = atomicAdd(&lcnt[wave], 1); if (sl < CAP) nbr[wave][sl] = b4 + 1; }
        if (v.z != 0.0f) { int sl = atomicAdd(&lcnt[wave], 1); if (sl < CAP) nbr[wave][sl] = b4 + 2; }
        if (v.w != 0.0f) { int sl = atomicAdd(&lcnt[wave], 1); if (sl < CAP) nbr[wave][sl] = b4 + 3; }
    }

    // ---- per-node scalars: r = xc@Wr + br ; s = (xc@We + be)@w_emb ----
    float pr = 0.0f, ps = 0.0f;
    if (lane < 32) {
        const float xc = (lane < 16) ? x[g * 16 + lane] : comms[g * 16 + (lane - 16)];
        float we = 0.0f;
#pragma unroll
        for (int c = 0; c < 8; ++c) we += We[lane * 8 + c] * w_emb[c];
        pr = xc * Wr[lane];
        ps = xc * we;
    } else if (lane == 32) {
#pragma unroll
        for (int c = 0; c < 8; ++c) ps += be[c] * w_emb[c];
        pr = br[0];
    }
#pragma unroll
    for (int off = 32; off; off >>= 1) { pr += __shfl_xor(pr, off); ps += __shfl_xor(ps, off); }
    const float r = pr, s = ps;

    const int   deg  = lcnt[wave];
    const int   cl   = deg < CAP ? deg : CAP;
    const int   clp  = cl < SLOT ? cl : SLOT;         // published slot count
    const float dinv = sqrtf(1.0f / ((float)deg + EPSF));
    const float p    = dinv * (s + b_emb[0]);

    // ---- publish node data + CSR row (agent atomics; drained at barrier) --
    if (lane == 0) {
        __hip_atomic_store(PD  + g, pk2(p, dinv), __ATOMIC_RELAXED, __HIP_MEMORY_SCOPE_AGENT);
        __hip_atomic_store(RS  + g, pk2(r, s),    __ATOMIC_RELAXED, __HIP_MEMORY_SCOPE_AGENT);
        __hip_atomic_store(UF0 + g, r,            __ATOMIC_RELAXED, __HIP_MEMORY_SCOPE_AGENT);
        __hip_atomic_store(CNT + g, clp,          __ATOMIC_RELAXED, __HIP_MEMORY_SCOPE_AGENT);
    }
    if (lane < clp)
        __hip_atomic_store(CSRG + g * SLOT + lane, nbr[wave][lane],
                           __ATOMIC_RELAXED, __HIP_MEMORY_SCOPE_AGENT);
    if (64 + lane < clp)
        __hip_atomic_store(CSRG + g * SLOT + 64 + lane, nbr[wave][64 + lane],
                           __ATOMIC_RELAXED, __HIP_MEMORY_SCOPE_AGENT);

    // ---- Phase-1 grid barrier (256 arrivals) with RETIREMENT ----
    __syncthreads();                      // drains all publishes (r4-r8 chain)
    if (tid == 0)
        __hip_atomic_store(arr + blockIdx.x, 1, __ATOMIC_RELAXED, __HIP_MEMORY_SCOPE_AGENT);
    if (blockIdx.x >= NB2) return;        // 224 blocks retire (stores are posted)
    if (blockIdx.x == 0) {
        if (tid < 64) {                   // master wave: detect all 256 arrivals
            const int base = tid * 4;
            for (;;) {
                const int a0 = __hip_atomic_load(arr + base + 0, __ATOMIC_RELAXED, __HIP_MEMORY_SCOPE_AGENT);
                const int a1 = __hip_atomic_load(arr + base + 1, __ATOMIC_RELAXED, __HIP_MEMORY_SCOPE_AGENT);
                const int a2 = __hip_atomic_load(arr + base + 2, __ATOMIC_RELAXED, __HIP_MEMORY_SCOPE_AGENT);
                const int a3 = __hip_atomic_load(arr + base + 3, __ATOMIC_RELAXED, __HIP_MEMORY_SCOPE_AGENT);
                if (__all((a0 >= 1) && (a1 >= 1) && (a2 >= 1) && (a3 >= 1))) break;
                __builtin_amdgcn_s_sleep(1);
            }
            if (tid < NB2)                // release only the 32 survivors
                __hip_atomic_store(rel + (size_t)tid * RELSTR, 1,
                                   __ATOMIC_RELAXED, __HIP_MEMORY_SCOPE_AGENT);
        }
    } else if (tid == 0) {
        while (__hip_atomic_load(rel + (size_t)blockIdx.x * RELSTR,
                                 __ATOMIC_RELAXED, __HIP_MEMORY_SCOPE_AGENT) < 1)
            __builtin_amdgcn_s_sleep(1);
    }
    __syncthreads();

    // ======================= Phase 2: 32 survivor blocks ====================
    // PD sweep -> LDS (sc1 vector path; barrier-fresh; r12-validated)
    {
        unsigned long long w0, w1, w2, w3;
        asm volatile(
            "global_load_dwordx2 %0, %4, off sc1\n\t"
            "global_load_dwordx2 %1, %5, off sc1\n\t"
            "global_load_dwordx2 %2, %6, off sc1\n\t"
            "global_load_dwordx2 %3, %7, off sc1\n\t"
            "s_waitcnt vmcnt(0)"
            : "=&v"(w0), "=&v"(w1), "=&v"(w2), "=&v"(w3)
            : "v"(PD + tid), "v"(PD + tid + 1024),
              "v"(PD + tid + 2048), "v"(PD + tid + 3072)
            : "memory");
        PDL[tid] = w0; PDL[tid + 1024] = w1;
        PDL[tid + 2048] = w2; PDL[tid + 3072] = w3;
    }
    __syncthreads();

    // per-thread edge setup: node n = bid*128 + q, sub-thread owns slots
    // sub, sub+8, ..., <=80. One-time scattered reads (atomic path OK here).
    const int q   = tid >> 3, sub = tid & 7;
    const int n   = (int)blockIdx.x * NPB2 + q;
    const int dgn = __hip_atomic_load(CNT + n, __ATOMIC_RELAXED, __HIP_MEMORY_SCOPE_AGENT);
    int jj[MAXE]; float pe[MAXE], de[MAXE];
#pragma unroll
    for (int e = 0; e < MAXE; ++e) {
        const int k  = sub + (e << 3);
        const bool vv = k < dgn;                  // dgn <= SLOT
        const int idx = n * SLOT + (vv ? k : 0);  // slot 0 always written (self)
        const int j   = __hip_atomic_load(CSRG + idx, __ATOMIC_RELAXED, __HIP_MEMORY_SCOPE_AGENT);
        jj[e] = vv ? j : 0;                       // any 0..4095 safe; coef 0 below
        const unsigned long long z = PDL[jj[e]];
        pe[e] = vv ? lo_f(z) : 0.0f;
        de[e] = vv ? hi_f(z) : 0.0f;
    }
    float rn = 0.0f, sn = 0.0f, dvn = 0.0f;
    if (sub == 0) {
        const unsigned long long z = __hip_atomic_load(RS + n, __ATOMIC_RELAXED, __HIP_MEMORY_SCOPE_AGENT);
        rn = lo_f(z); sn = hi_f(z); dvn = hi_f(PDL[n]);
    }
    float wa[8], bb[8];
#pragma unroll
    for (int c = 0; c < 8; ++c) { wa[c] = Wa[c]; bb[c] = ba[c]; }

    // ---- 10 VI steps: sweep(16KB) -> gather -> 8-lane reduce -> publish ----
    float v = 0.0f;
    for (int t = 0; t < KSTEPS; ++t) {
        const float* Uf = (t & 1) ? UF1 : UF0;
        float*       Uo = (t & 1) ? UF0 : UF1;
        {
            float f0, f1, f2, f3;
            asm volatile(
                "global_load_dword %0, %4, off sc1\n\t"
                "global_load_dword %1, %5, off sc1\n\t"
                "global_load_dword %2, %6, off sc1\n\t"
                "global_load_dword %3, %7, off sc1\n\t"
                "s_waitcnt vmcnt(0)"
                : "=&v"(f0), "=&v"(f1), "=&v"(f2), "=&v"(f3)
                : "v"(Uf + tid), "v"(Uf + tid + 1024),
                  "v"(Uf + tid + 2048), "v"(Uf + tid + 3072)
                : "memory");
            UL[tid] = f0; UL[tid + 1024] = f1;
            UL[tid + 2048] = f2; UL[tid + 3072] = f3;
        }
        __syncthreads();                          // plane copy complete

        float a1 = 0.0f, a2 = 0.0f;               // S1 = sum p_j u_j, S2 = sum d_j u_j
#pragma unroll
        for (int e = 0; e < MAXE; ++e) {
            const float u = UL[jj[e]];
            a1 = fmaf(pe[e], u, a1);
            a2 = fmaf(de[e], u, a2);
        }
        a1 += __shfl_xor(a1, 1); a2 += __shfl_xor(a2, 1);   // reduce 8-lane group
        a1 += __shfl_xor(a1, 2); a2 += __shfl_xor(a2, 2);
        a1 += __shfl_xor(a1, 4); a2 += __shfl_xor(a2, 4);

        if (sub == 0) {
            const float k3v = dvn * (a1 - sn * a2);
            v = fmaf(k3v, wa[0], bb[0]);
#pragma unroll
            for (int c = 1; c < 8; ++c) v = fmaxf(v, fmaf(k3v, wa[c], bb[c]));
            if (t < KSTEPS - 1)
                __hip_atomic_store(Uo + n, rn + GAMMA * v,
                                   __ATOMIC_RELAXED, __HIP_MEMORY_SCOPE_AGENT);
        }
        if (t < KSTEPS - 1)
            grid_barrier32(arr, rel, t + 2);      // publishes drained -> fresh sweep
    }

    if (sub == 0) out[n] = v + (mask[n] == 0.0f ? -INFINITY : 0.0f);
}

extern "C" void kernel_launch(void* const* d_in, const int* in_sizes, int n_in,
                              void* d_out, int out_size, void* d_ws, size_t ws_size,
                              hipStream_t stream) {
    const float* x     = (const float*)d_in[0];
    const float* comms = (const float*)d_in[1];
    const float* adj   = (const float*)d_in[2];
    const float* mask  = (const float*)d_in[3];
    const float* Wr    = (const float*)d_in[4];
    const float* br    = (const float*)d_in[5];
    const float* We    = (const float*)d_in[6];
    const float* be    = (const float*)d_in[7];
    const float* w_emb = (const float*)d_in[8];
    const float* b_emb = (const float*)d_in[9];
    const float* Wa    = (const float*)d_in[10];
    const float* ba    = (const float*)d_in[11];
    // d_in[12] = k (fixed at 10, hardcoded)

    // ws: arr 4KB | rel 4KB | PD 32KB | RS 32KB | UF0 16KB | UF1 16KB |
    //     CNT 16KB | CSRG 1.25MB  (~1.4MB total). Poison-safe, no memset:
    // barrier flags monotonic (poison negative); planes read only after the
    // barrier ordering their writes; CSR clamp targets slot 0 (always written).
    char* ws = (char*)d_ws;
    size_t off = 0;
    int* arr               = (int*)(ws + off); off += 4096;
    int* rel               = (int*)(ws + off); off += 4096;
    unsigned long long* PD = (unsigned long long*)(ws + off); off += (size_t)NN * 8;
    unsigned long long* RS = (unsigned long long*)(ws + off); off += (size_t)NN * 8;
    float* UF0             = (float*)(ws + off); off += (size_t)NN * 4;
    float* UF1             = (float*)(ws + off); off += (size_t)NN * 4;
    int* CNT               = (int*)(ws + off); off += (size_t)NN * 4;
    int* CSRG              = (int*)(ws + off); off += (size_t)NN * SLOT * 4;
    float* out = (float*)d_out;

    // PLAIN launch: 256 blocks, 1/CU co-resident by capacity (16 waves,
    // ~57 KB LDS of 160 KB, VGPR < 128). Validated r4-r12 at this shape.
    gvin_retire<<<dim3(NB), dim3(TPB), 0, stream>>>(
        adj, x, comms, mask, Wr, br, We, be, w_emb, b_emb, Wa, ba,
        arr, rel, PD, RS, UF0, UF1, CNT, CSRG, out);
}